// Round 6
// baseline (183.939 us; speedup 1.0000x reference)
//
#include <hip/hip_runtime.h>

typedef _Float16 half8 __attribute__((ext_vector_type(8)));
typedef float f32x16 __attribute__((ext_vector_type(16)));

__device__ __forceinline__ void gld_lds16(const void* g, void* l) {
  __builtin_amdgcn_global_load_lds(
      (const __attribute__((address_space(1))) void*)g,
      (__attribute__((address_space(3))) void*)l, 16, 0, 0);
}

#define SB() __builtin_amdgcn_sched_barrier(0)
#define LGKM0() asm volatile("s_waitcnt lgkmcnt(0)" ::: "memory")
#define LGKM8() asm volatile("s_waitcnt lgkmcnt(8)" ::: "memory")
#define VMC(n) asm volatile("s_waitcnt vmcnt(" #n ")" ::: "memory")
#define BAR() __builtin_amdgcn_s_barrier()
#define PRIO1() __builtin_amdgcn_s_setprio(1)
#define PRIO0() __builtin_amdgcn_s_setprio(0)

// All GEMMs: C = A·B^T, f16 operands, fp32 accum, 32x32x16 MFMA.
// LDS tiles stored [row][64] f16 with 16B-granule XOR swizzle (slot = g ^ (row&7)).
// A-frag for (rowblk, ks): lane reads row rowblk+(lane&31), granule ks*2+hi.
// C/D: col = lane&31, row = (j&3) + 8*(j>>2) + 4*hi  (j = 0..15).

// ---------------- scores: A=Q,B=K from QKV[8192,3072]; 256 wg, tile 256x256 --
__global__ __launch_bounds__(512, 2) void gemm32s(const _Float16* __restrict__ QKV,
                                                  _Float16* __restrict__ Sc) {
  int g = (int)blockIdx.x;
  g = (g & 7) * 32 + (g >> 3);
  const int z = g >> 6, r = g & 63, tm = r >> 3, tn = r & 7;
  const int row0 = tm * 256, col0 = tn * 256;
  const _Float16* Ap = QKV + ((size_t)z * 2048 + row0) * 3072;
  const _Float16* Bp = QKV + ((size_t)z * 2048 + col0) * 3072 + 1024;
  _Float16* C16 = Sc + (size_t)z * 4194304;

  __shared__ _Float16 lds[65536];  // [par][A 16384 | B 16384]
  const int tid = threadIdx.x, lane = tid & 63, wid = tid >> 6;
  const int wm = wid >> 2, wn = wid & 3;  // 2M x 4N, per-wave 128x64
  const int l31 = lane & 31, hi = lane >> 5, r7 = l31 & 7;
  const int srow = tid >> 3;
  const int sgl = (((tid & 7) ^ (srow & 7)) << 3);

  f32x16 acc[4][2] = {};
  half8 aF[8], bF0[4], bF1[4];

  auto stage = [&](const _Float16* Gp, int rowoff, int kt, int dstbase) {
    gld_lds16(Gp + (size_t)(rowoff + srow) * 3072 + kt + sgl, &lds[dstbase + tid * 8]);
  };
  auto stageT = [&](int kt, int par) {  // 8 gld
#pragma unroll
    for (int h = 0; h < 4; ++h) stage(Ap, h * 64, kt, par * 32768 + h * 4096);
#pragma unroll
    for (int h = 0; h < 4; ++h) stage(Bp, h * 64, kt, par * 32768 + 16384 + h * 4096);
  };
  auto ldA = [&](int par, int qmh) {
    const int base = par * 32768 + (wm * 128 + qmh * 64 + l31) * 64;
#pragma unroll
    for (int mb = 0; mb < 2; ++mb)
#pragma unroll
      for (int ks = 0; ks < 4; ++ks)
        aF[mb * 4 + ks] = *(const half8*)&lds[base + mb * 2048 + (((ks * 2 + hi) ^ r7) << 3)];
  };
  auto ldB = [&](int par, int nb, half8* bF) {
    const int base = par * 32768 + 16384 + (wn * 64 + nb * 32 + l31) * 64;
#pragma unroll
    for (int ks = 0; ks < 4; ++ks)
      bF[ks] = *(const half8*)&lds[base + (((ks * 2 + hi) ^ r7) << 3)];
  };
  auto burst = [&](int qmh, int nb, const half8* bF) {  // 8 MFMA
#pragma unroll
    for (int ks = 0; ks < 4; ++ks)
#pragma unroll
      for (int ml = 0; ml < 2; ++ml)
        acc[qmh * 2 + ml][nb] = __builtin_amdgcn_mfma_f32_32x32x16_f16(
            aF[ml * 4 + ks], bF[ks], acc[qmh * 2 + ml][nb], 0, 0, 0);
  };

  stageT(0, 0);
  stageT(64, 1);
  VMC(8); BAR();
  constexpr int NK = 16;
#pragma unroll 1
  for (int t = 0; t < NK; ++t) {
    const int par = t & 1;
    // P1
    ldA(par, 0); SB(); ldB(par, 0, bF0); SB(); LGKM8();
    BAR(); LGKM0(); SB(); PRIO1(); burst(0, 0, bF0); PRIO0(); SB(); BAR();
    // P2
    ldB(par, 1, bF1); SB();
    BAR(); LGKM0(); SB(); PRIO1(); burst(0, 1, bF1); PRIO0(); SB(); BAR();
    // P3
    ldA(par, 1); SB();
    BAR(); LGKM0(); SB(); PRIO1(); burst(1, 0, bF0); PRIO0(); SB(); BAR();
    // P4: stage t+2 (all tile-t LDS reads completed by P3-close) + reg-only MFMA
    if (t + 2 < NK) stageT(t * 64 + 128, par);
    SB(); PRIO1(); burst(1, 1, bF1); PRIO0(); SB();
    if (t + 2 < NK) { VMC(8); } else if (t + 1 < NK) { VMC(0); }
    BAR();
  }

  const int cb = col0 + wn * 64 + l31;
#pragma unroll
  for (int mb = 0; mb < 4; ++mb)
#pragma unroll
    for (int nb = 0; nb < 2; ++nb) {
      const int col = cb + nb * 32;
#pragma unroll
      for (int j = 0; j < 16; ++j) {
        const int row = row0 + wm * 128 + mb * 32 + (j & 3) + ((j >> 2) << 3) + hi * 4;
        C16[(size_t)row * 2048 + col] = (_Float16)acc[mb][nb][j];
      }
    }
}

// -------- QKV: A=x16[8192,1024], B=Wcat[3072,1024]; 512 wg, tile 128x384 ----
__global__ __launch_bounds__(512, 2) void gemm32q(const _Float16* __restrict__ Ag,
                                                  const _Float16* __restrict__ Bg,
                                                  _Float16* __restrict__ Cg,
                                                  const float* __restrict__ bcat) {
  int g = (int)blockIdx.x;
  g = (g & 7) * 64 + (g >> 3);
  const int tm = g >> 3, tn = g & 7;
  const int row0 = tm * 128, col0 = tn * 384;
  const _Float16* Ap = Ag + (size_t)row0 * 1024;
  const _Float16* Bp = Bg + (size_t)col0 * 1024;

  __shared__ _Float16 lds[65536];  // [par][A 8192 | B 24576]
  const int tid = threadIdx.x, lane = tid & 63, wid = tid >> 6;
  const int wm = wid >> 2, wn = wid & 3;  // 2M x 4N, per-wave 64x96
  const int l31 = lane & 31, hi = lane >> 5, r7 = l31 & 7;
  const int srow = tid >> 3;
  const int sgl = (((tid & 7) ^ (srow & 7)) << 3);

  f32x16 acc[2][3] = {};
  half8 aF[8], bF[3][4];

  auto stage = [&](const _Float16* Gp, int rowoff, int kt, int dstbase) {
    gld_lds16(Gp + (size_t)(rowoff + srow) * 1024 + kt + sgl, &lds[dstbase + tid * 8]);
  };
  auto stageT = [&](int kt, int par) {  // 8 gld
#pragma unroll
    for (int h = 0; h < 2; ++h) stage(Ap, h * 64, kt, par * 32768 + h * 4096);
#pragma unroll
    for (int h = 0; h < 6; ++h) stage(Bp, h * 64, kt, par * 32768 + 8192 + h * 4096);
  };
  auto ldA = [&](int par) {
    const int base = par * 32768 + (wm * 64 + l31) * 64;
#pragma unroll
    for (int mb = 0; mb < 2; ++mb)
#pragma unroll
      for (int ks = 0; ks < 4; ++ks)
        aF[mb * 4 + ks] = *(const half8*)&lds[base + mb * 2048 + (((ks * 2 + hi) ^ r7) << 3)];
  };
  auto ldB = [&](int par, int nb) {
    const int base = par * 32768 + 8192 + (wn * 96 + nb * 32 + l31) * 64;
#pragma unroll
    for (int ks = 0; ks < 4; ++ks)
      bF[nb][ks] = *(const half8*)&lds[base + (((ks * 2 + hi) ^ r7) << 3)];
  };
  auto burst = [&](int nb) {  // 8 MFMA
#pragma unroll
    for (int ks = 0; ks < 4; ++ks)
#pragma unroll
      for (int mb = 0; mb < 2; ++mb)
        acc[mb][nb] = __builtin_amdgcn_mfma_f32_32x32x16_f16(
            aF[mb * 4 + ks], bF[nb][ks], acc[mb][nb], 0, 0, 0);
  };

  stageT(0, 0);
  VMC(0); BAR();
  constexpr int NK = 16;
#pragma unroll 1
  for (int t = 0; t < NK; ++t) {
    const int par = t & 1;
    // P1: ds reads + stage(t+1 -> other parity; prior tile's reads done at P3-close)
    ldA(par); SB(); ldB(par, 0); SB();
    if (t + 1 < NK) stageT(t * 64 + 64, par ^ 1);
    SB(); LGKM8();
    BAR(); LGKM0(); SB(); PRIO1(); burst(0); PRIO0(); SB(); BAR();
    // P2
    ldB(par, 1); SB();
    BAR(); LGKM0(); SB(); PRIO1(); burst(1); PRIO0(); SB(); BAR();
    // P3
    ldB(par, 2); SB();
    BAR(); LGKM0(); SB(); PRIO1(); burst(2); PRIO0(); SB();
    if (t + 1 < NK) VMC(0);  // t+1 issued ~2.5 phases ago: wait ~0
    BAR();
  }

  const int cb = col0 + wn * 96 + l31;
#pragma unroll
  for (int mb = 0; mb < 2; ++mb)
#pragma unroll
    for (int nb = 0; nb < 3; ++nb) {
      const int col = cb + nb * 32;
      const float badd = bcat[col];
#pragma unroll
      for (int j = 0; j < 16; ++j) {
        const int row = row0 + wm * 64 + mb * 32 + (j & 3) + ((j >> 2) << 3) + hi * 4;
        Cg[(size_t)row * 3072 + col] = (_Float16)(acc[mb][nb][j] + badd);
      }
    }
}

// -------- PV: A=Sc[z][2048,2048], B=Vt[z][1024,2048]; 256 wg, tile 256x128 ---
__global__ __launch_bounds__(512, 2) void gemm32p(const _Float16* __restrict__ Scp,
                                                  const _Float16* __restrict__ Vt,
                                                  float* __restrict__ Out) {
  int g = (int)blockIdx.x;
  g = (g & 7) * 32 + (g >> 3);
  const int z = g >> 6, r = g & 63, tm = r >> 3, tn = r & 7;
  const int row0 = tm * 256, col0 = tn * 128;
  const _Float16* Ap = Scp + (size_t)z * 4194304 + (size_t)row0 * 2048;
  const _Float16* Bp = Vt + (size_t)z * 2097152 + (size_t)col0 * 2048;
  float* C32 = Out + (size_t)z * 2097152;

  __shared__ _Float16 lds[49152];  // [par][A 16384 | B 8192]
  const int tid = threadIdx.x, lane = tid & 63, wid = tid >> 6;
  const int wm = wid >> 1, wn = wid & 1;  // 4M x 2N, per-wave 64x64
  const int l31 = lane & 31, hi = lane >> 5, r7 = l31 & 7;
  const int srow = tid >> 3;
  const int sgl = (((tid & 7) ^ (srow & 7)) << 3);

  f32x16 acc[2][2] = {};
  half8 aF[8], bF0[4], bF1[4];

  auto stage = [&](const _Float16* Gp, int rowoff, int kt, int dstbase) {
    gld_lds16(Gp + (size_t)(rowoff + srow) * 2048 + kt + sgl, &lds[dstbase + tid * 8]);
  };
  auto stageT = [&](int kt, int par) {  // 6 gld
#pragma unroll
    for (int h = 0; h < 4; ++h) stage(Ap, h * 64, kt, par * 24576 + h * 4096);
#pragma unroll
    for (int h = 0; h < 2; ++h) stage(Bp, h * 64, kt, par * 24576 + 16384 + h * 4096);
  };
  auto ldA = [&](int par) {
    const int base = par * 24576 + (wm * 64 + l31) * 64;
#pragma unroll
    for (int mb = 0; mb < 2; ++mb)
#pragma unroll
      for (int ks = 0; ks < 4; ++ks)
        aF[mb * 4 + ks] = *(const half8*)&lds[base + mb * 2048 + (((ks * 2 + hi) ^ r7) << 3)];
  };
  auto ldB = [&](int par, int nb, half8* bF) {
    const int base = par * 24576 + 16384 + (wn * 64 + nb * 32 + l31) * 64;
#pragma unroll
    for (int ks = 0; ks < 4; ++ks)
      bF[ks] = *(const half8*)&lds[base + (((ks * 2 + hi) ^ r7) << 3)];
  };
  auto burst = [&](int nb, const half8* bF) {  // 8 MFMA
#pragma unroll
    for (int ks = 0; ks < 4; ++ks)
#pragma unroll
      for (int mb = 0; mb < 2; ++mb)
        acc[mb][nb] = __builtin_amdgcn_mfma_f32_32x32x16_f16(
            aF[mb * 4 + ks], bF[ks], acc[mb][nb], 0, 0, 0);
  };

  stageT(0, 0);
  VMC(0); BAR();
  constexpr int NK = 32;
#pragma unroll 1
  for (int t = 0; t < NK; ++t) {
    const int par = t & 1;
    // P1
    ldA(par); SB(); ldB(par, 0, bF0); SB();
    if (t + 1 < NK) stageT(t * 64 + 64, par ^ 1);
    SB(); LGKM8();
    BAR(); LGKM0(); SB(); PRIO1(); burst(0, bF0); PRIO0(); SB(); BAR();
    // P2
    ldB(par, 1, bF1); SB();
    BAR(); LGKM0(); SB(); PRIO1(); burst(1, bF1); PRIO0(); SB();
    if (t + 1 < NK) VMC(0);
    BAR();
  }

  const int cb = col0 + wn * 64 + l31;
#pragma unroll
  for (int mb = 0; mb < 2; ++mb)
#pragma unroll
    for (int nb = 0; nb < 2; ++nb) {
      const int col = cb + nb * 32;
#pragma unroll
      for (int j = 0; j < 16; ++j) {
        const int row = row0 + wm * 64 + mb * 32 + (j & 3) + ((j >> 2) << 3) + hi * 4;
        C32[(size_t)row * 1024 + col] = acc[mb][nb][j];
      }
    }
}

// ---------------------------------------------------------------------------
__global__ void cvt_f32_f16(const float* __restrict__ in, _Float16* __restrict__ out, int n8) {
  int i = blockIdx.x * blockDim.x + threadIdx.x;
  const int stride = gridDim.x * blockDim.x;
  for (; i < n8; i += stride) {
    const float4* p = (const float4*)(in + (size_t)i * 8);
    float4 a = p[0], b = p[1];
    half8 h;
    h[0] = (_Float16)a.x; h[1] = (_Float16)a.y; h[2] = (_Float16)a.z; h[3] = (_Float16)a.w;
    h[4] = (_Float16)b.x; h[5] = (_Float16)b.y; h[6] = (_Float16)b.z; h[7] = (_Float16)b.w;
    *(half8*)(out + (size_t)i * 8) = h;
  }
}

__global__ void cvt3_w(const float* __restrict__ wq, const float* __restrict__ wk,
                       const float* __restrict__ wv, _Float16* __restrict__ out) {
  const float* in = blockIdx.y == 0 ? wq : (blockIdx.y == 1 ? wk : wv);
  _Float16* o = out + (size_t)blockIdx.y * 1048576;
  const int i = blockIdx.x * blockDim.x + threadIdx.x;
  const float4* p = (const float4*)(in + (size_t)i * 8);
  float4 a = p[0], b = p[1];
  half8 h;
  h[0] = (_Float16)a.x; h[1] = (_Float16)a.y; h[2] = (_Float16)a.z; h[3] = (_Float16)a.w;
  h[4] = (_Float16)b.x; h[5] = (_Float16)b.y; h[6] = (_Float16)b.z; h[7] = (_Float16)b.w;
  *(half8*)(o + (size_t)i * 8) = h;
}

__global__ void bias_cat(const float* __restrict__ a, const float* __restrict__ b,
                         const float* __restrict__ c, float* __restrict__ o) {
  const int i = blockIdx.x * 256 + threadIdx.x;
  const float* s = i < 1024 ? a : (i < 2048 ? b : c);
  o[i] = s[i & 1023];
}

// V = QKV cols 2048.. (stride 3072) -> Vt[4][1024][2048]
__global__ __launch_bounds__(256) void transpose_v(const _Float16* __restrict__ QKV,
                                                   _Float16* __restrict__ Vt) {
  __shared__ _Float16 t[32][36];
  const int b = blockIdx.z;
  const int e0 = blockIdx.x * 32;
  const int s0 = blockIdx.y * 32;
  const int tid = threadIdx.x;
  const int r = tid >> 3;
  const int c4 = (tid & 7) * 4;
  const _Float16* src = QKV + (size_t)(b * 2048 + s0 + r) * 3072 + 2048 + e0 + c4;
#pragma unroll
  for (int j = 0; j < 4; ++j) t[r][c4 + j] = src[j];
  __syncthreads();
  _Float16* dst = Vt + ((size_t)b * 1024 + e0 + r) * 2048 + s0 + c4;
#pragma unroll
  for (int j = 0; j < 4; ++j) dst[j] = t[c4 + j][r];
}

__global__ __launch_bounds__(256) void softmax_rows_f16(_Float16* __restrict__ S) {
  __shared__ float red[4];
  _Float16* s = S + (size_t)blockIdx.x * 2048;
  const int tid = threadIdx.x;
  float v[8];
  {
    half8 h = *(const half8*)(s + tid * 8);
#pragma unroll
    for (int j = 0; j < 8; ++j) v[j] = (float)h[j];
  }
  float m = v[0];
#pragma unroll
  for (int j = 1; j < 8; ++j) m = fmaxf(m, v[j]);
#pragma unroll
  for (int off = 32; off > 0; off >>= 1) m = fmaxf(m, __shfl_xor(m, off));
  if ((tid & 63) == 0) red[tid >> 6] = m;
  __syncthreads();
  m = fmaxf(fmaxf(red[0], red[1]), fmaxf(red[2], red[3]));
  float sum = 0.f;
#pragma unroll
  for (int j = 0; j < 8; ++j) { v[j] = __expf(v[j] - m); sum += v[j]; }
#pragma unroll
  for (int off = 32; off > 0; off >>= 1) sum += __shfl_xor(sum, off);
  __syncthreads();
  if ((tid & 63) == 0) red[tid >> 6] = sum;
  __syncthreads();
  sum = red[0] + red[1] + red[2] + red[3];
  const float inv = 1.0f / sum;
  half8 h;
#pragma unroll
  for (int j = 0; j < 8; ++j) h[j] = (_Float16)(v[j] * inv);
  *(half8*)(s + tid * 8) = h;
}

extern "C" void kernel_launch(void* const* d_in, const int* in_sizes, int n_in,
                              void* d_out, int out_size, void* d_ws, size_t ws_size,
                              hipStream_t stream) {
  (void)in_sizes; (void)n_in; (void)out_size;
  const float* x  = (const float*)d_in[0];
  const float* Wq = (const float*)d_in[1];
  const float* bq = (const float*)d_in[2];
  const float* Wk = (const float*)d_in[3];
  const float* bk = (const float*)d_in[4];
  const float* Wv = (const float*)d_in[5];
  const float* bv = (const float*)d_in[6];
  float* out = (float*)d_out;

  char* ws = (char*)d_ws;
  size_t off = 0;
  auto alloc = [&](size_t bytes) {
    char* p = ws + off;
    off += (bytes + 255) & ~255ull;
    return p;
  };
  _Float16* x16  = (_Float16*)alloc(8192ull * 1024 * 2);
  _Float16* W16  = (_Float16*)alloc(3072ull * 1024 * 2);
  _Float16* QKV  = (_Float16*)alloc(8192ull * 3072 * 2);
  _Float16* Vt   = (_Float16*)alloc(4096ull * 1024 * 4);
  _Float16* Sc   = (_Float16*)alloc(4ull * 2048 * 2048 * 2);
  float*    bcat = (float*)alloc(3072 * 4);
  if (off > ws_size) return;

  cvt_f32_f16<<<2048, 256, 0, stream>>>(x, x16, 8192 * 1024 / 8);
  cvt3_w<<<dim3(512, 3), 256, 0, stream>>>(Wq, Wk, Wv, W16);
  bias_cat<<<12, 256, 0, stream>>>(bq, bk, bv, bcat);

  gemm32q<<<512, 512, 0, stream>>>(x16, W16, QKV, bcat);
  transpose_v<<<dim3(32, 64, 4), 256, 0, stream>>>(QKV, Vt);

  gemm32s<<<256, 512, 0, stream>>>(QKV, Sc);
  softmax_rows_f16<<<8192, 256, 0, stream>>>(Sc);
  gemm32p<<<256, 512, 0, stream>>>(Sc, Vt, out);
}

// Round 7
// 162.979 us; speedup vs baseline: 1.1286x; 1.1286x over previous
//
#include <hip/hip_runtime.h>

typedef _Float16 half8 __attribute__((ext_vector_type(8)));
typedef float floatx4 __attribute__((ext_vector_type(4)));

__device__ __forceinline__ void gld_lds16(const void* g, void* l) {
  __builtin_amdgcn_global_load_lds(
      (const __attribute__((address_space(1))) void*)g,
      (__attribute__((address_space(3))) void*)l, 16, 0, 0);
}

#define SB() __builtin_amdgcn_sched_barrier(0)
#define LGKM(n) asm volatile("s_waitcnt lgkmcnt(" #n ")" ::: "memory")
#define VMC0() asm volatile("s_waitcnt vmcnt(0)" ::: "memory")
#define BAR() __builtin_amdgcn_s_barrier()
#define PRIO1() __builtin_amdgcn_s_setprio(1)
#define PRIO0() __builtin_amdgcn_s_setprio(0)

// ===== 1-barrier ring GEMM: C = A·B^T, f16 in, fp32 accum, 16x16x32 MFMA ====
// Ring: stage(t+1 -> parity^1) at TOP of tile t (WAR-safe: t-1 readers did
// LGKM(0)+BAR before this issues). End of tile t: VMC(0) (issued ~2000cyc ago,
// ~free) + BAR publishes LDS for all waves. MFMA gated by descending lgkmcnt.
// MODE 0: QKV  A=x16[8192,1024] B=Wcat[3072,1024] -> f16[8192,3072]+bias, 512wg tile 256x192, waves 4Mx2N
// MODE 1: SC   A,B=QKV (Q cols 0-1023 / K cols 1024-2047) -> f16 scores, 256wg tile 256x256, waves 2Mx4N
// MODE 2: PV   A=Sc[z] B=Vt[z] K=2048 -> f32 out, 256wg tile 256x128, waves 4Mx2N
template <int MODE>
__global__ __launch_bounds__(512, 2) void gemmr(
    const _Float16* __restrict__ Ag, const _Float16* __restrict__ Bg,
    void* __restrict__ Cg, const float* __restrict__ bcat) {
  constexpr int TN   = MODE == 0 ? 192 : (MODE == 1 ? 256 : 128);
  constexpr int KS   = MODE == 0 ? 1024 : (MODE == 1 ? 3072 : 2048);
  constexpr int NK   = MODE == 2 ? 32 : 16;
  constexpr int NWG  = MODE == 0 ? 512 : 256;
  constexpr int WN   = MODE == 1 ? 4 : 2;   // waves across N
  constexpr int NMF  = MODE == 1 ? 8 : 4;   // 16-row A frags per wave
  constexpr int NNF  = TN / 16 / WN;        // 6 / 4 / 4
  constexpr int ASL  = 16384;               // A slot elems (256x64)
  constexpr int BSL  = TN * 64;             // B slot elems
  constexpr int NSB  = TN / 64;             // B stage chunks
  constexpr int CSTR = MODE == 0 ? 3072 : (MODE == 1 ? 2048 : 1024);

  int g = (int)blockIdx.x;
  g = (g & 7) * (NWG / 8) + (g >> 3);  // XCD swizzle (NWG % 8 == 0)

  int row0, col0;
  const _Float16 *Ap, *Bp;
  _Float16* C16 = nullptr;
  float* C32 = nullptr;
  if constexpr (MODE == 0) {
    const int tm = g >> 4, tn = g & 15;
    row0 = tm * 256; col0 = tn * 192;
    Ap = Ag + (size_t)row0 * 1024;
    Bp = Bg + (size_t)col0 * 1024;
    C16 = (_Float16*)Cg;
  } else if constexpr (MODE == 1) {
    const int z = g >> 6, r = g & 63, tm = r >> 3, tn = r & 7;
    row0 = tm * 256; col0 = tn * 256;
    Ap = Ag + (size_t)z * 6291456 + (size_t)row0 * 3072;
    Bp = Ag + (size_t)z * 6291456 + (size_t)col0 * 3072 + 1024;
    C16 = (_Float16*)Cg + (size_t)z * 4194304;
  } else {
    const int z = g >> 6, r = g & 63, tm = r >> 3, tn = r & 7;
    row0 = tm * 256; col0 = tn * 128;
    Ap = Ag + (size_t)z * 4194304 + (size_t)row0 * 2048;
    Bp = Bg + (size_t)z * 2097152 + (size_t)col0 * 2048;
    C32 = (float*)Cg + (size_t)z * 2097152;
  }

  __shared__ _Float16 lds[2 * ASL + 2 * BSL];
  const int tid = threadIdx.x, lane = tid & 63, wid = tid >> 6;
  const int wm = MODE == 1 ? (wid >> 2) : (wid >> 1);
  const int wn = MODE == 1 ? (wid & 3) : (wid & 1);
  const int wrow = wm * (NMF * 16);
  const int wcol = wn * (NNF * 16);
  const int fr = lane & 15, u = lane >> 4, w7 = lane & 7;
  const int k0e = ((u ^ w7) << 3), k1e = (((4 + u) ^ w7) << 3);
  const int srow = tid >> 3;
  const int sgl = (((tid & 7) ^ (srow & 7)) << 3);

  floatx4 acc[NMF][NNF] = {};
  half8 aF[NMF * 2], bF[NNF * 2];

  auto stage1 = [&](const _Float16* Gp, int rowoff, int kt, int dst) {
    gld_lds16(Gp + (size_t)(rowoff + srow) * KS + kt + sgl, &lds[dst + tid * 8]);
  };
  auto stageT = [&](int kt, int p) {
#pragma unroll
    for (int c = 0; c < 4; ++c) stage1(Ap, c * 64, kt, p * ASL + c * 4096);
#pragma unroll
    for (int c = 0; c < NSB; ++c)
      stage1(Bp, c * 64, kt, 2 * ASL + p * BSL + c * 4096);
  };
  auto ldA4 = [&](int p, int mf0) {  // 8 ds_read_b128
#pragma unroll
    for (int mf = 0; mf < 4; ++mf) {
      const int ro = p * ASL + (wrow + (mf0 + mf) * 16 + fr) * 64;
      aF[(mf0 + mf) * 2 + 0] = *(const half8*)&lds[ro + k0e];
      aF[(mf0 + mf) * 2 + 1] = *(const half8*)&lds[ro + k1e];
    }
  };
  auto ldB2 = [&](int p, int nf0) {  // 4 ds_read_b128
#pragma unroll
    for (int nf = 0; nf < 2; ++nf) {
      const int ro = 2 * ASL + p * BSL + (wcol + (nf0 + nf) * 16 + fr) * 64;
      bF[(nf0 + nf) * 2 + 0] = *(const half8*)&lds[ro + k0e];
      bF[(nf0 + nf) * 2 + 1] = *(const half8*)&lds[ro + k1e];
    }
  };
  auto burst = [&](int mf0, int nf0) {  // 16 MFMA
#pragma unroll
    for (int mf = 0; mf < 4; ++mf)
#pragma unroll
      for (int nf = 0; nf < 2; ++nf)
#pragma unroll
        for (int kk = 0; kk < 2; ++kk)
          acc[mf0 + mf][nf0 + nf] = __builtin_amdgcn_mfma_f32_16x16x32_f16(
              aF[(mf0 + mf) * 2 + kk], bF[(nf0 + nf) * 2 + kk],
              acc[mf0 + mf][nf0 + nf], 0, 0, 0);
  };

  // prologue
  stageT(0, 0);
  VMC0();
  BAR();

#pragma unroll 1
  for (int t = 0; t < NK; ++t) {
    const int p = t & 1;
    if (t + 1 < NK) stageT(t * 64 + 64, p ^ 1);
    SB();
    if constexpr (MODE == 1) {
      // issue: aF[0:8](mf0-3) bF[0:4] bF[4:8] aF[8:16](mf4-7)  = 24 reads
      ldA4(p, 0); SB(); ldB2(p, 0); SB(); ldB2(p, 2); SB(); ldA4(p, 4); SB();
      LGKM(12); SB(); PRIO1(); burst(0, 0); PRIO0(); SB();
      LGKM(8);  SB(); PRIO1(); burst(0, 2); PRIO0(); SB();
      LGKM(0);  SB(); PRIO1(); burst(4, 0); burst(4, 2); PRIO0(); SB();
    } else if constexpr (MODE == 0) {
      // issue: aF(8) bF[0:4] bF[4:8] bF[8:12] = 20 reads
      ldA4(p, 0); SB(); ldB2(p, 0); SB(); ldB2(p, 2); SB(); ldB2(p, 4); SB();
      LGKM(8); SB(); PRIO1(); burst(0, 0); PRIO0(); SB();
      LGKM(4); SB(); PRIO1(); burst(0, 2); PRIO0(); SB();
      LGKM(0); SB(); PRIO1(); burst(0, 4); PRIO0(); SB();
    } else {
      // issue: aF(8) bF[0:4] bF[4:8] = 16 reads
      ldA4(p, 0); SB(); ldB2(p, 0); SB(); ldB2(p, 2); SB();
      LGKM(4); SB(); PRIO1(); burst(0, 0); PRIO0(); SB();
      LGKM(0); SB(); PRIO1(); burst(0, 2); PRIO0(); SB();
    }
    if (t + 1 < NK) VMC0();  // stage(t+1) issued a full tile ago -> ~free
    BAR();                    // publish t+1 LDS to all waves
  }

  // epilogue: row = row0+wrow+mf*16+u*4+j, col = col0+wcol+nf*16+fr
  const int r0 = row0 + wrow + u * 4;
  const int c0 = col0 + wcol + fr;
#pragma unroll
  for (int mf = 0; mf < NMF; ++mf)
#pragma unroll
    for (int nf = 0; nf < NNF; ++nf) {
      const int col = c0 + nf * 16;
      float badd = 0.f;
      if constexpr (MODE == 0) badd = bcat[col];
#pragma unroll
      for (int j = 0; j < 4; ++j) {
        const int row = r0 + mf * 16 + j;
        if constexpr (MODE == 2)
          C32[(size_t)row * CSTR + col] = acc[mf][nf][j];
        else
          C16[(size_t)row * CSTR + col] = (_Float16)(acc[mf][nf][j] + badd);
      }
    }
}

// ---------------------------------------------------------------------------
__global__ void cvt_f32_f16(const float* __restrict__ in, _Float16* __restrict__ out, int n8) {
  int i = blockIdx.x * blockDim.x + threadIdx.x;
  const int stride = gridDim.x * blockDim.x;
  for (; i < n8; i += stride) {
    const float4* p = (const float4*)(in + (size_t)i * 8);
    float4 a = p[0], b = p[1];
    half8 h;
    h[0] = (_Float16)a.x; h[1] = (_Float16)a.y; h[2] = (_Float16)a.z; h[3] = (_Float16)a.w;
    h[4] = (_Float16)b.x; h[5] = (_Float16)b.y; h[6] = (_Float16)b.z; h[7] = (_Float16)b.w;
    *(half8*)(out + (size_t)i * 8) = h;
  }
}

__global__ void cvt3_w(const float* __restrict__ wq, const float* __restrict__ wk,
                       const float* __restrict__ wv, _Float16* __restrict__ out) {
  const float* in = blockIdx.y == 0 ? wq : (blockIdx.y == 1 ? wk : wv);
  _Float16* o = out + (size_t)blockIdx.y * 1048576;
  const int i = blockIdx.x * blockDim.x + threadIdx.x;
  const float4* p = (const float4*)(in + (size_t)i * 8);
  float4 a = p[0], b = p[1];
  half8 h;
  h[0] = (_Float16)a.x; h[1] = (_Float16)a.y; h[2] = (_Float16)a.z; h[3] = (_Float16)a.w;
  h[4] = (_Float16)b.x; h[5] = (_Float16)b.y; h[6] = (_Float16)b.z; h[7] = (_Float16)b.w;
  *(half8*)(o + (size_t)i * 8) = h;
}

__global__ void bias_cat(const float* __restrict__ a, const float* __restrict__ b,
                         const float* __restrict__ c, float* __restrict__ o) {
  const int i = blockIdx.x * 256 + threadIdx.x;
  const float* s = i < 1024 ? a : (i < 2048 ? b : c);
  o[i] = s[i & 1023];
}

// V = QKV cols 2048.. (stride 3072) -> Vt[4][1024][2048]
__global__ __launch_bounds__(256) void transpose_v(const _Float16* __restrict__ QKV,
                                                   _Float16* __restrict__ Vt) {
  __shared__ _Float16 t[32][36];
  const int b = blockIdx.z;
  const int e0 = blockIdx.x * 32;
  const int s0 = blockIdx.y * 32;
  const int tid = threadIdx.x;
  const int r = tid >> 3;
  const int c4 = (tid & 7) * 4;
  const _Float16* src = QKV + (size_t)(b * 2048 + s0 + r) * 3072 + 2048 + e0 + c4;
#pragma unroll
  for (int j = 0; j < 4; ++j) t[r][c4 + j] = src[j];
  __syncthreads();
  _Float16* dst = Vt + ((size_t)b * 1024 + e0 + r) * 2048 + s0 + c4;
#pragma unroll
  for (int j = 0; j < 4; ++j) dst[j] = t[c4 + j][r];
}

__global__ __launch_bounds__(256) void softmax_rows_f16(_Float16* __restrict__ S) {
  __shared__ float red[4];
  _Float16* s = S + (size_t)blockIdx.x * 2048;
  const int tid = threadIdx.x;
  float v[8];
  {
    half8 h = *(const half8*)(s + tid * 8);
#pragma unroll
    for (int j = 0; j < 8; ++j) v[j] = (float)h[j];
  }
  float m = v[0];
#pragma unroll
  for (int j = 1; j < 8; ++j) m = fmaxf(m, v[j]);
#pragma unroll
  for (int off = 32; off > 0; off >>= 1) m = fmaxf(m, __shfl_xor(m, off));
  if ((tid & 63) == 0) red[tid >> 6] = m;
  __syncthreads();
  m = fmaxf(fmaxf(red[0], red[1]), fmaxf(red[2], red[3]));
  float sum = 0.f;
#pragma unroll
  for (int j = 0; j < 8; ++j) { v[j] = __expf(v[j] - m); sum += v[j]; }
#pragma unroll
  for (int off = 32; off > 0; off >>= 1) sum += __shfl_xor(sum, off);
  __syncthreads();
  if ((tid & 63) == 0) red[tid >> 6] = sum;
  __syncthreads();
  sum = red[0] + red[1] + red[2] + red[3];
  const float inv = 1.0f / sum;
  half8 h;
#pragma unroll
  for (int j = 0; j < 8; ++j) h[j] = (_Float16)(v[j] * inv);
  *(half8*)(s + tid * 8) = h;
}

extern "C" void kernel_launch(void* const* d_in, const int* in_sizes, int n_in,
                              void* d_out, int out_size, void* d_ws, size_t ws_size,
                              hipStream_t stream) {
  (void)in_sizes; (void)n_in; (void)out_size;
  const float* x  = (const float*)d_in[0];
  const float* Wq = (const float*)d_in[1];
  const float* bq = (const float*)d_in[2];
  const float* Wk = (const float*)d_in[3];
  const float* bk = (const float*)d_in[4];
  const float* Wv = (const float*)d_in[5];
  const float* bv = (const float*)d_in[6];
  float* out = (float*)d_out;

  char* ws = (char*)d_ws;
  size_t off = 0;
  auto alloc = [&](size_t bytes) {
    char* p = ws + off;
    off += (bytes + 255) & ~255ull;
    return p;
  };
  _Float16* x16  = (_Float16*)alloc(8192ull * 1024 * 2);
  _Float16* W16  = (_Float16*)alloc(3072ull * 1024 * 2);
  _Float16* QKV  = (_Float16*)alloc(8192ull * 3072 * 2);
  _Float16* Vt   = (_Float16*)alloc(4096ull * 1024 * 4);
  _Float16* Sc   = (_Float16*)alloc(4ull * 2048 * 2048 * 2);
  float*    bcat = (float*)alloc(3072 * 4);
  if (off > ws_size) return;

  cvt_f32_f16<<<2048, 256, 0, stream>>>(x, x16, 8192 * 1024 / 8);
  cvt3_w<<<dim3(512, 3), 256, 0, stream>>>(Wq, Wk, Wv, W16);
  bias_cat<<<12, 256, 0, stream>>>(bq, bk, bv, bcat);

  gemmr<0><<<512, 512, 0, stream>>>(x16, W16, QKV, bcat);
  transpose_v<<<dim3(32, 64, 4), 256, 0, stream>>>(QKV, Vt);

  gemmr<1><<<256, 512, 0, stream>>>(QKV, QKV, Sc, nullptr);
  softmax_rows_f16<<<8192, 256, 0, stream>>>(Sc);
  gemmr<2><<<256, 512, 0, stream>>>(Sc, Vt, out, nullptr);
}

// Round 8
// 158.838 us; speedup vs baseline: 1.1580x; 1.0261x over previous
//
#include <hip/hip_runtime.h>

typedef _Float16 half8 __attribute__((ext_vector_type(8)));
typedef float floatx4 __attribute__((ext_vector_type(4)));

__device__ __forceinline__ void gld_lds16(const void* g, void* l) {
  __builtin_amdgcn_global_load_lds(
      (const __attribute__((address_space(1))) void*)g,
      (__attribute__((address_space(3))) void*)l, 16, 0, 0);
}

#define SB() __builtin_amdgcn_sched_barrier(0)
#define LGKM(n) asm volatile("s_waitcnt lgkmcnt(" #n ")" ::: "memory")
#define VMC0() asm volatile("s_waitcnt vmcnt(0)" ::: "memory")
#define BAR() __builtin_amdgcn_s_barrier()
#define PRIO1() __builtin_amdgcn_s_setprio(1)
#define PRIO0() __builtin_amdgcn_s_setprio(0)

// ===== desync ring GEMM: 128x128 tile, BK=64, 4 waves, 64KB LDS, 2 wg/CU ====
// C = A·B^T, f16 in, fp32 accum, 16x16x32 MFMA. Ring schedule identical to R7
// (stage t+1 at top, counted-lgkm bursts, one VMC0+BAR per tile); the change
// is occupancy: two INDEPENDENT wgs per CU so barrier stalls interleave.
// MODE 0: QKV  A=x16[8192,1024] B=Wcat[3072,1024] -> f16[8192,3072]+bias, 1536 wg
// MODE 1: SC   A,B=QKV (Q cols 0-1023 / K cols 1024-2047, stride 3072) -> f16, 1024 wg
// MODE 2: PV   A=Sc[z][2048,2048] B=Vt[z][1024,2048] -> f32 out, 512 wg
template <int MODE>
__global__ __launch_bounds__(256, 2) void gemmd(
    const _Float16* __restrict__ Ag, const _Float16* __restrict__ Bg,
    void* __restrict__ Cg, const float* __restrict__ bcat) {
  constexpr int KS   = MODE == 0 ? 1024 : (MODE == 1 ? 3072 : 2048);
  constexpr int NK   = MODE == 2 ? 32 : 16;
  constexpr int NWG  = MODE == 0 ? 1536 : (MODE == 1 ? 1024 : 512);
  constexpr int CSTR = MODE == 0 ? 3072 : (MODE == 1 ? 2048 : 1024);

  int g = (int)blockIdx.x;
  g = (g & 7) * (NWG / 8) + (g >> 3);  // XCD swizzle (NWG % 8 == 0)

  int row0, col0;
  const _Float16 *Ap, *Bp;
  _Float16* C16 = nullptr;
  float* C32 = nullptr;
  if constexpr (MODE == 0) {
    const int tm = g / 24, tn = g % 24;
    row0 = tm * 128; col0 = tn * 128;
    Ap = Ag + (size_t)row0 * 1024;
    Bp = Bg + (size_t)col0 * 1024;
    C16 = (_Float16*)Cg;
  } else if constexpr (MODE == 1) {
    const int z = g >> 8, r = g & 255, tm = r >> 4, tn = r & 15;
    row0 = tm * 128; col0 = tn * 128;
    Ap = Ag + (size_t)z * 6291456 + (size_t)row0 * 3072;
    Bp = Ag + (size_t)z * 6291456 + (size_t)col0 * 3072 + 1024;
    C16 = (_Float16*)Cg + (size_t)z * 4194304;
  } else {
    const int z = g >> 7, r = g & 127, tm = r >> 3, tn = r & 7;
    row0 = tm * 128; col0 = tn * 128;
    Ap = Ag + (size_t)z * 4194304 + (size_t)row0 * 2048;
    Bp = Bg + (size_t)z * 2097152 + (size_t)col0 * 2048;
    C32 = (float*)Cg + (size_t)z * 2097152;
  }

  __shared__ _Float16 lds[32768];  // 64KB: A[2][8192] @0, B[2][8192] @16384
  const int tid = threadIdx.x, lane = tid & 63, wid = tid >> 6;
  const int wm = wid >> 1, wn = wid & 1;
  const int wrow = wm * 64, wcol = wn * 64;
  const int fr = lane & 15, u = lane >> 4, w7 = lane & 7;
  const int k0e = ((u ^ w7) << 3), k1e = (((4 + u) ^ w7) << 3);
  const int srow = tid >> 3;  // 0..31 (32-row stage chunks)
  const int sgl = (((tid & 7) ^ (srow & 7)) << 3);

  floatx4 acc[4][4] = {};
  half8 aF[8], bF[8];

  auto stage1 = [&](const _Float16* Gp, int rowoff, int kt, int dst) {
    gld_lds16(Gp + (size_t)(rowoff + srow) * KS + kt + sgl, &lds[dst + tid * 8]);
  };
  auto stageT = [&](int kt, int p) {  // 8 gld: A 4 chunks + B 4 chunks
#pragma unroll
    for (int c = 0; c < 4; ++c) stage1(Ap, c * 32, kt, p * 8192 + c * 2048);
#pragma unroll
    for (int c = 0; c < 4; ++c) stage1(Bp, c * 32, kt, 16384 + p * 8192 + c * 2048);
  };
  auto ldA4 = [&](int p) {  // 8 ds_read_b128
#pragma unroll
    for (int mf = 0; mf < 4; ++mf) {
      const int ro = p * 8192 + (wrow + mf * 16 + fr) * 64;
      aF[mf * 2 + 0] = *(const half8*)&lds[ro + k0e];
      aF[mf * 2 + 1] = *(const half8*)&lds[ro + k1e];
    }
  };
  auto ldB2 = [&](int p, int nf0) {  // 4 ds_read_b128
#pragma unroll
    for (int nf = 0; nf < 2; ++nf) {
      const int ro = 16384 + p * 8192 + (wcol + (nf0 + nf) * 16 + fr) * 64;
      bF[(nf0 + nf) * 2 + 0] = *(const half8*)&lds[ro + k0e];
      bF[(nf0 + nf) * 2 + 1] = *(const half8*)&lds[ro + k1e];
    }
  };
  auto burst = [&](int nf0) {  // 16 MFMA
#pragma unroll
    for (int mf = 0; mf < 4; ++mf)
#pragma unroll
      for (int nf = 0; nf < 2; ++nf)
#pragma unroll
        for (int kk = 0; kk < 2; ++kk)
          acc[mf][nf0 + nf] = __builtin_amdgcn_mfma_f32_16x16x32_f16(
              aF[mf * 2 + kk], bF[(nf0 + nf) * 2 + kk], acc[mf][nf0 + nf], 0, 0, 0);
  };

  stageT(0, 0);
  VMC0();
  BAR();

#pragma unroll 1
  for (int t = 0; t < NK; ++t) {
    const int p = t & 1;
    if (t + 1 < NK) stageT(t * 64 + 64, p ^ 1);
    SB();
    // issue: aF(8) bF[0:4](4) bF[4:8](4) = 16 reads
    ldA4(p); SB(); ldB2(p, 0); SB(); ldB2(p, 2); SB();
    LGKM(4); SB(); PRIO1(); burst(0); PRIO0(); SB();
    LGKM(0); SB(); PRIO1(); burst(2); PRIO0(); SB();
    if (t + 1 < NK) VMC0();  // stage(t+1) issued a full tile ago
    BAR();                    // publish buffer p^1 to all waves
  }

  const int r0 = row0 + wrow + u * 4;
  const int c0 = col0 + wcol + fr;
#pragma unroll
  for (int mf = 0; mf < 4; ++mf)
#pragma unroll
    for (int nf = 0; nf < 4; ++nf) {
      const int col = c0 + nf * 16;
      float badd = 0.f;
      if constexpr (MODE == 0) badd = bcat[col];
#pragma unroll
      for (int j = 0; j < 4; ++j) {
        const int row = r0 + mf * 16 + j;
        if constexpr (MODE == 2)
          C32[(size_t)row * CSTR + col] = acc[mf][nf][j];
        else
          C16[(size_t)row * CSTR + col] = (_Float16)(acc[mf][nf][j] + badd);
      }
    }
}

// --------- fused prep: x cvt (blocks 0..2047), W cvt (2048..3583), bias ------
__global__ __launch_bounds__(256) void prep(
    const float* __restrict__ x, const float* __restrict__ wq,
    const float* __restrict__ wk, const float* __restrict__ wv,
    const float* __restrict__ bq, const float* __restrict__ bk,
    const float* __restrict__ bv, _Float16* __restrict__ x16,
    _Float16* __restrict__ W16, float* __restrict__ bcat) {
  const int b = blockIdx.x, t = threadIdx.x;
  auto cv8 = [](const float* src, _Float16* dst) {
    const float4* p = (const float4*)src;
    float4 a = p[0], bb = p[1];
    half8 h;
    h[0] = (_Float16)a.x; h[1] = (_Float16)a.y; h[2] = (_Float16)a.z; h[3] = (_Float16)a.w;
    h[4] = (_Float16)bb.x; h[5] = (_Float16)bb.y; h[6] = (_Float16)bb.z; h[7] = (_Float16)bb.w;
    *(half8*)dst = h;
  };
  if (b < 2048) {
    const int i = b * 256 + t;
#pragma unroll
    for (int c = 0; c < 2; ++c) {
      const size_t j = (size_t)(i + c * 524288) * 8;
      cv8(x + j, x16 + j);
    }
  } else if (b < 3584) {
    const int idx = (b - 2048) * 256 + t;  // [0, 393216)
    const int m = idx >> 17, j = idx & 131071;
    const float* src = m == 0 ? wq : (m == 1 ? wk : wv);
    cv8(src + (size_t)j * 8, W16 + (size_t)m * 1048576 + (size_t)j * 8);
  } else {
    const int i = (b - 3584) * 256 + t;  // [0, 3072)
    const float* s = i < 1024 ? bq : (i < 2048 ? bk : bv);
    bcat[i] = s[i & 1023];
  }
}

// V = QKV cols 2048.. (stride 3072) -> Vt[4][1024][2048]
__global__ __launch_bounds__(256) void transpose_v(const _Float16* __restrict__ QKV,
                                                   _Float16* __restrict__ Vt) {
  __shared__ _Float16 t[32][36];
  const int b = blockIdx.z;
  const int e0 = blockIdx.x * 32;
  const int s0 = blockIdx.y * 32;
  const int tid = threadIdx.x;
  const int r = tid >> 3;
  const int c4 = (tid & 7) * 4;
  const _Float16* src = QKV + (size_t)(b * 2048 + s0 + r) * 3072 + 2048 + e0 + c4;
#pragma unroll
  for (int j = 0; j < 4; ++j) t[r][c4 + j] = src[j];
  __syncthreads();
  _Float16* dst = Vt + ((size_t)b * 1024 + e0 + r) * 2048 + s0 + c4;
#pragma unroll
  for (int j = 0; j < 4; ++j) dst[j] = t[c4 + j][r];
}

__global__ __launch_bounds__(256) void softmax_rows_f16(_Float16* __restrict__ S) {
  __shared__ float red[4];
  _Float16* s = S + (size_t)blockIdx.x * 2048;
  const int tid = threadIdx.x;
  float v[8];
  {
    half8 h = *(const half8*)(s + tid * 8);
#pragma unroll
    for (int j = 0; j < 8; ++j) v[j] = (float)h[j];
  }
  float m = v[0];
#pragma unroll
  for (int j = 1; j < 8; ++j) m = fmaxf(m, v[j]);
#pragma unroll
  for (int off = 32; off > 0; off >>= 1) m = fmaxf(m, __shfl_xor(m, off));
  if ((tid & 63) == 0) red[tid >> 6] = m;
  __syncthreads();
  m = fmaxf(fmaxf(red[0], red[1]), fmaxf(red[2], red[3]));
  float sum = 0.f;
#pragma unroll
  for (int j = 0; j < 8; ++j) { v[j] = __expf(v[j] - m); sum += v[j]; }
#pragma unroll
  for (int off = 32; off > 0; off >>= 1) sum += __shfl_xor(sum, off);
  __syncthreads();
  if ((tid & 63) == 0) red[tid >> 6] = sum;
  __syncthreads();
  sum = red[0] + red[1] + red[2] + red[3];
  const float inv = 1.0f / sum;
  half8 h;
#pragma unroll
  for (int j = 0; j < 8; ++j) h[j] = (_Float16)(v[j] * inv);
  *(half8*)(s + tid * 8) = h;
}

extern "C" void kernel_launch(void* const* d_in, const int* in_sizes, int n_in,
                              void* d_out, int out_size, void* d_ws, size_t ws_size,
                              hipStream_t stream) {
  (void)in_sizes; (void)n_in; (void)out_size;
  const float* x  = (const float*)d_in[0];
  const float* Wq = (const float*)d_in[1];
  const float* bq = (const float*)d_in[2];
  const float* Wk = (const float*)d_in[3];
  const float* bk = (const float*)d_in[4];
  const float* Wv = (const float*)d_in[5];
  const float* bv = (const float*)d_in[6];
  float* out = (float*)d_out;

  char* ws = (char*)d_ws;
  size_t off = 0;
  auto alloc = [&](size_t bytes) {
    char* p = ws + off;
    off += (bytes + 255) & ~255ull;
    return p;
  };
  _Float16* x16  = (_Float16*)alloc(8192ull * 1024 * 2);
  _Float16* W16  = (_Float16*)alloc(3072ull * 1024 * 2);
  _Float16* QKV  = (_Float16*)alloc(8192ull * 3072 * 2);
  _Float16* Vt   = (_Float16*)alloc(4096ull * 1024 * 4);
  _Float16* Sc   = (_Float16*)alloc(4ull * 2048 * 2048 * 2);
  float*    bcat = (float*)alloc(3072 * 4);
  if (off > ws_size) return;

  prep<<<3596, 256, 0, stream>>>(x, Wq, Wk, Wv, bq, bk, bv, x16, W16, bcat);

  gemmd<0><<<1536, 256, 0, stream>>>(x16, W16, QKV, bcat);
  transpose_v<<<dim3(32, 64, 4), 256, 0, stream>>>(QKV, Vt);

  gemmd<1><<<1024, 256, 0, stream>>>(QKV, QKV, Sc, nullptr);
  softmax_rows_f16<<<8192, 256, 0, stream>>>(Sc);
  gemmd<2><<<512, 256, 0, stream>>>(Sc, Vt, out, nullptr);
}

// Round 9
// 158.815 us; speedup vs baseline: 1.1582x; 1.0001x over previous
//
#include <hip/hip_runtime.h>

typedef _Float16 half8 __attribute__((ext_vector_type(8)));
typedef float floatx4 __attribute__((ext_vector_type(4)));

__device__ __forceinline__ void gld_lds16(const void* g, void* l) {
  __builtin_amdgcn_global_load_lds(
      (const __attribute__((address_space(1))) void*)g,
      (__attribute__((address_space(3))) void*)l, 16, 0, 0);
}

#define SB() __builtin_amdgcn_sched_barrier(0)
#define LGKM(n) asm volatile("s_waitcnt lgkmcnt(" #n ")" ::: "memory")
#define VMC(n) asm volatile("s_waitcnt vmcnt(" #n ")" ::: "memory")
#define BAR() __builtin_amdgcn_s_barrier()
#define PRIO1() __builtin_amdgcn_s_setprio(1)
#define PRIO0() __builtin_amdgcn_s_setprio(0)

// ======== scores: m201-style 256x256 8-phase, A=Q B=K (stride 3072) =========
// 8 waves 2Mx4N (per-wave 128x64), BK=64, 128KB LDS, 256 wgs (1 round).
// Ring: P1/P2 stage A(t+1)->parity p^1; P3/P4 stage B(t+2)->parity p.
// Counted waits (FIFO-derived, steady state):
//  P2-end VMC(8): retires A(t)h1 before P3 reads it        [10 outstanding]
//  P4-end VMC(6): retires A(t+1)h0 + all B(t+1) before t+1 [12 outstanding]
__global__ __launch_bounds__(512, 2) void gemm8x(const _Float16* __restrict__ QKV,
                                                 _Float16* __restrict__ Sc) {
  int g = (int)blockIdx.x;
  g = (g & 7) * 32 + (g >> 3);  // XCD swizzle, 256 % 8 == 0
  const int z = g >> 6, r = g & 63, tm = r >> 3, tn = r & 7;
  const int row0 = tm * 256, col0 = tn * 256;
  const _Float16* Ap = QKV + ((size_t)z * 2048 + row0) * 3072;
  const _Float16* Bp = QKV + ((size_t)z * 2048 + col0) * 3072 + 1024;
  _Float16* C16 = Sc + (size_t)z * 4194304;

  __shared__ _Float16 lds[65536];  // A[2][16384] @0, B[2][16384] @32768
  const int tid = threadIdx.x, lane = tid & 63, wid = tid >> 6;
  const int wm = wid >> 2, wn = wid & 3;
  const int fr = lane & 15, u = lane >> 4, w7 = lane & 7;
  const int k0e = ((u ^ w7) << 3), k1e = (((4 + u) ^ w7) << 3);
  const int srow = tid >> 3;
  const int sgl = (((tid & 7) ^ (srow & 7)) << 3);

  floatx4 acc[8][4] = {};
  half8 aF[8], bF0[4], bF1[4];

  auto stg = [&](const _Float16* Gp, int rowoff, int kt, int dst) {
    gld_lds16(Gp + (size_t)(rowoff + srow) * 3072 + kt + sgl, &lds[dst + tid * 8]);
  };
  auto stA = [&](int kt, int p, int h) {  // 2 gld_lds (128 rows)
    stg(Ap, h * 128, kt, p * 16384 + h * 8192);
    stg(Ap, h * 128 + 64, kt, p * 16384 + h * 8192 + 4096);
  };
  auto stB = [&](int kt, int p, int h) {
    stg(Bp, h * 128, kt, 32768 + p * 16384 + h * 8192);
    stg(Bp, h * 128 + 64, kt, 32768 + p * 16384 + h * 8192 + 4096);
  };
  auto ldA = [&](int p, int mh) {  // 8 ds_read_b128
#pragma unroll
    for (int mf = 0; mf < 4; ++mf) {
      const int ro = p * 16384 + (wm * 128 + mh * 64 + mf * 16 + fr) * 64;
      aF[mf * 2 + 0] = *(const half8*)&lds[ro + k0e];
      aF[mf * 2 + 1] = *(const half8*)&lds[ro + k1e];
    }
  };
  auto ldB = [&](int p, int nh, half8* bF) {  // 4 ds_read_b128
#pragma unroll
    for (int nf = 0; nf < 2; ++nf) {
      const int ro = 32768 + p * 16384 + (wn * 64 + nh * 32 + nf * 16 + fr) * 64;
      bF[nf * 2 + 0] = *(const half8*)&lds[ro + k0e];
      bF[nf * 2 + 1] = *(const half8*)&lds[ro + k1e];
    }
  };
  auto Q = [&](int mh, int nh, half8* bF) {  // 16 MFMA
#pragma unroll
    for (int mf = 0; mf < 4; ++mf)
#pragma unroll
      for (int nf = 0; nf < 2; ++nf)
#pragma unroll
        for (int kk = 0; kk < 2; ++kk)
          acc[mh * 4 + mf][nh * 2 + nf] = __builtin_amdgcn_mfma_f32_16x16x32_f16(
              aF[mf * 2 + kk], bF[nf * 2 + kk], acc[mh * 4 + mf][nh * 2 + nf], 0, 0, 0);
  };

  // prologue: A(0) h0,h1; B(0) h0,h1; B(1) h0,h1  (12 loads) -> retain B(1)
  stA(0, 0, 0); stA(0, 0, 1); stB(0, 0, 0); stB(0, 0, 1);
  stB(64, 1, 0); stB(64, 1, 1);
  VMC(4); BAR();

  constexpr int NK = 16;
#pragma unroll 1
  for (int t = 0; t < NK; ++t) {
    const int p = t & 1, kt = t * 64;
    // P1: ldA h0 (8) + ldB h0 (4) + stage A(t+1)h0
    ldA(p, 0); SB(); ldB(p, 0, bF0); SB();
    if (t + 1 < NK) stA(kt + 64, p ^ 1, 0);
    SB(); LGKM(8); SB();
    BAR(); LGKM(0); SB(); PRIO1(); Q(0, 0, bF0); PRIO0(); SB(); BAR();
    // P2: ldB h1 (4) + stage A(t+1)h1 ; VMC(8) guards P3's A(t)h1 read
    ldB(p, 1, bF1); SB();
    if (t + 1 < NK) stA(kt + 64, p ^ 1, 1);
    SB();
    BAR(); LGKM(0); SB(); PRIO1(); Q(0, 1, bF1); PRIO0(); SB(); VMC(8); BAR();
    // P3: ldA h1 (8) + stage B(t+2)h0 (B(t) slot freed: all waves passed P2 lgkm0)
    ldA(p, 1); SB();
    if (t + 2 < NK) stB(kt + 128, p, 0);
    SB();
    BAR(); LGKM(0); SB(); PRIO1(); Q(1, 0, bF0); PRIO0(); SB(); BAR();
    // P4: stage B(t+2)h1 + reg-only MFMA ; VMC(6) readies tile t+1
    if (t + 2 < NK) stB(kt + 128, p, 1);
    SB();
    BAR(); PRIO1(); Q(1, 1, bF1); PRIO0(); SB();
    if (t + 2 < NK) { VMC(6); } else if (t + 1 < NK) { VMC(0); }
    BAR();
  }

  const int r0 = row0 + wm * 128 + u * 4;
  const int c0 = col0 + wn * 64 + fr;
#pragma unroll
  for (int mf = 0; mf < 8; ++mf)
#pragma unroll
    for (int nf = 0; nf < 4; ++nf)
#pragma unroll
      for (int j = 0; j < 4; ++j)
        C16[(size_t)(r0 + mf * 16 + j) * 2048 + c0 + nf * 16] = (_Float16)acc[mf][nf][j];
}

// ===== desync ring GEMM (R8): 128x128 tile, BK=64, 4 waves, 2 wg/CU =========
// MODE 0: QKV  A=x16[8192,1024] B=Wcat[3072,1024] -> f16[8192,3072]+bias, 1536 wg
// MODE 2: PV   A=Sc[z][2048,2048] B=Vt[z][1024,2048] -> f32 out, 512 wg
template <int MODE>
__global__ __launch_bounds__(256, 2) void gemmd(
    const _Float16* __restrict__ Ag, const _Float16* __restrict__ Bg,
    void* __restrict__ Cg, const float* __restrict__ bcat) {
  constexpr int KS   = MODE == 0 ? 1024 : 2048;
  constexpr int NK   = MODE == 2 ? 32 : 16;
  constexpr int NWG  = MODE == 0 ? 1536 : 512;
  constexpr int CSTR = MODE == 0 ? 3072 : 1024;

  int g = (int)blockIdx.x;
  g = (g & 7) * (NWG / 8) + (g >> 3);

  int row0, col0;
  const _Float16 *Ap, *Bp;
  _Float16* C16 = nullptr;
  float* C32 = nullptr;
  if constexpr (MODE == 0) {
    const int tm = g / 24, tn = g % 24;
    row0 = tm * 128; col0 = tn * 128;
    Ap = Ag + (size_t)row0 * 1024;
    Bp = Bg + (size_t)col0 * 1024;
    C16 = (_Float16*)Cg;
  } else {
    const int z = g >> 7, r = g & 127, tm = r >> 3, tn = r & 7;
    row0 = tm * 128; col0 = tn * 128;
    Ap = Ag + (size_t)z * 4194304 + (size_t)row0 * 2048;
    Bp = Bg + (size_t)z * 2097152 + (size_t)col0 * 2048;
    C32 = (float*)Cg + (size_t)z * 2097152;
  }

  __shared__ _Float16 lds[32768];
  const int tid = threadIdx.x, lane = tid & 63, wid = tid >> 6;
  const int wm = wid >> 1, wn = wid & 1;
  const int wrow = wm * 64, wcol = wn * 64;
  const int fr = lane & 15, u = lane >> 4, w7 = lane & 7;
  const int k0e = ((u ^ w7) << 3), k1e = (((4 + u) ^ w7) << 3);
  const int srow = tid >> 3;
  const int sgl = (((tid & 7) ^ (srow & 7)) << 3);

  floatx4 acc[4][4] = {};
  half8 aF[8], bF[8];

  auto stage1 = [&](const _Float16* Gp, int rowoff, int kt, int dst) {
    gld_lds16(Gp + (size_t)(rowoff + srow) * KS + kt + sgl, &lds[dst + tid * 8]);
  };
  auto stageT = [&](int kt, int p) {
#pragma unroll
    for (int c = 0; c < 4; ++c) stage1(Ap, c * 32, kt, p * 8192 + c * 2048);
#pragma unroll
    for (int c = 0; c < 4; ++c) stage1(Bp, c * 32, kt, 16384 + p * 8192 + c * 2048);
  };
  auto ldA4 = [&](int p) {
#pragma unroll
    for (int mf = 0; mf < 4; ++mf) {
      const int ro = p * 8192 + (wrow + mf * 16 + fr) * 64;
      aF[mf * 2 + 0] = *(const half8*)&lds[ro + k0e];
      aF[mf * 2 + 1] = *(const half8*)&lds[ro + k1e];
    }
  };
  auto ldB2 = [&](int p, int nf0) {
#pragma unroll
    for (int nf = 0; nf < 2; ++nf) {
      const int ro = 16384 + p * 8192 + (wcol + (nf0 + nf) * 16 + fr) * 64;
      bF[(nf0 + nf) * 2 + 0] = *(const half8*)&lds[ro + k0e];
      bF[(nf0 + nf) * 2 + 1] = *(const half8*)&lds[ro + k1e];
    }
  };
  auto burst = [&](int nf0) {
#pragma unroll
    for (int mf = 0; mf < 4; ++mf)
#pragma unroll
      for (int nf = 0; nf < 2; ++nf)
#pragma unroll
        for (int kk = 0; kk < 2; ++kk)
          acc[mf][nf0 + nf] = __builtin_amdgcn_mfma_f32_16x16x32_f16(
              aF[mf * 2 + kk], bF[(nf0 + nf) * 2 + kk], acc[mf][nf0 + nf], 0, 0, 0);
  };

  stageT(0, 0);
  VMC(0);
  BAR();

#pragma unroll 1
  for (int t = 0; t < NK; ++t) {
    const int p = t & 1;
    if (t + 1 < NK) stageT(t * 64 + 64, p ^ 1);
    SB();
    ldA4(p); SB(); ldB2(p, 0); SB(); ldB2(p, 2); SB();
    LGKM(4); SB(); PRIO1(); burst(0); PRIO0(); SB();
    LGKM(0); SB(); PRIO1(); burst(2); PRIO0(); SB();
    if (t + 1 < NK) VMC(0);
    BAR();
  }

  const int r0 = row0 + wrow + u * 4;
  const int c0 = col0 + wcol + fr;
#pragma unroll
  for (int mf = 0; mf < 4; ++mf)
#pragma unroll
    for (int nf = 0; nf < 4; ++nf) {
      const int col = c0 + nf * 16;
      float badd = 0.f;
      if constexpr (MODE == 0) badd = bcat[col];
#pragma unroll
      for (int j = 0; j < 4; ++j) {
        const int row = r0 + mf * 16 + j;
        if constexpr (MODE == 2)
          C32[(size_t)row * CSTR + col] = acc[mf][nf][j];
        else
          C16[(size_t)row * CSTR + col] = (_Float16)(acc[mf][nf][j] + badd);
      }
    }
}

// --------- fused prep: x cvt (blocks 0..2047), W cvt (2048..3583), bias ------
__global__ __launch_bounds__(256) void prep(
    const float* __restrict__ x, const float* __restrict__ wq,
    const float* __restrict__ wk, const float* __restrict__ wv,
    const float* __restrict__ bq, const float* __restrict__ bk,
    const float* __restrict__ bv, _Float16* __restrict__ x16,
    _Float16* __restrict__ W16, float* __restrict__ bcat) {
  const int b = blockIdx.x, t = threadIdx.x;
  auto cv8 = [](const float* src, _Float16* dst) {
    const float4* p = (const float4*)src;
    float4 a = p[0], bb = p[1];
    half8 h;
    h[0] = (_Float16)a.x; h[1] = (_Float16)a.y; h[2] = (_Float16)a.z; h[3] = (_Float16)a.w;
    h[4] = (_Float16)bb.x; h[5] = (_Float16)bb.y; h[6] = (_Float16)bb.z; h[7] = (_Float16)bb.w;
    *(half8*)dst = h;
  };
  if (b < 2048) {
    const int i = b * 256 + t;
#pragma unroll
    for (int c = 0; c < 2; ++c) {
      const size_t j = (size_t)(i + c * 524288) * 8;
      cv8(x + j, x16 + j);
    }
  } else if (b < 3584) {
    const int idx = (b - 2048) * 256 + t;
    const int m = idx >> 17, j = idx & 131071;
    const float* src = m == 0 ? wq : (m == 1 ? wk : wv);
    cv8(src + (size_t)j * 8, W16 + (size_t)m * 1048576 + (size_t)j * 8);
  } else {
    const int i = (b - 3584) * 256 + t;
    const float* s = i < 1024 ? bq : (i < 2048 ? bk : bv);
    bcat[i] = s[i & 1023];
  }
}

// V = QKV cols 2048.. (stride 3072) -> Vt[4][1024][2048]
__global__ __launch_bounds__(256) void transpose_v(const _Float16* __restrict__ QKV,
                                                   _Float16* __restrict__ Vt) {
  __shared__ _Float16 t[32][36];
  const int b = blockIdx.z;
  const int e0 = blockIdx.x * 32;
  const int s0 = blockIdx.y * 32;
  const int tid = threadIdx.x;
  const int r = tid >> 3;
  const int c4 = (tid & 7) * 4;
  const _Float16* src = QKV + (size_t)(b * 2048 + s0 + r) * 3072 + 2048 + e0 + c4;
#pragma unroll
  for (int j = 0; j < 4; ++j) t[r][c4 + j] = src[j];
  __syncthreads();
  _Float16* dst = Vt + ((size_t)b * 1024 + e0 + r) * 2048 + s0 + c4;
#pragma unroll
  for (int j = 0; j < 4; ++j) dst[j] = t[c4 + j][r];
}

__global__ __launch_bounds__(256) void softmax_rows_f16(_Float16* __restrict__ S) {
  __shared__ float red[4];
  _Float16* s = S + (size_t)blockIdx.x * 2048;
  const int tid = threadIdx.x;
  float v[8];
  {
    half8 h = *(const half8*)(s + tid * 8);
#pragma unroll
    for (int j = 0; j < 8; ++j) v[j] = (float)h[j];
  }
  float m = v[0];
#pragma unroll
  for (int j = 1; j < 8; ++j) m = fmaxf(m, v[j]);
#pragma unroll
  for (int off = 32; off > 0; off >>= 1) m = fmaxf(m, __shfl_xor(m, off));
  if ((tid & 63) == 0) red[tid >> 6] = m;
  __syncthreads();
  m = fmaxf(fmaxf(red[0], red[1]), fmaxf(red[2], red[3]));
  float sum = 0.f;
#pragma unroll
  for (int j = 0; j < 8; ++j) { v[j] = __expf(v[j] - m); sum += v[j]; }
#pragma unroll
  for (int off = 32; off > 0; off >>= 1) sum += __shfl_xor(sum, off);
  __syncthreads();
  if ((tid & 63) == 0) red[tid >> 6] = sum;
  __syncthreads();
  sum = red[0] + red[1] + red[2] + red[3];
  const float inv = 1.0f / sum;
  half8 h;
#pragma unroll
  for (int j = 0; j < 8; ++j) h[j] = (_Float16)(v[j] * inv);
  *(half8*)(s + tid * 8) = h;
}

extern "C" void kernel_launch(void* const* d_in, const int* in_sizes, int n_in,
                              void* d_out, int out_size, void* d_ws, size_t ws_size,
                              hipStream_t stream) {
  (void)in_sizes; (void)n_in; (void)out_size;
  const float* x  = (const float*)d_in[0];
  const float* Wq = (const float*)d_in[1];
  const float* bq = (const float*)d_in[2];
  const float* Wk = (const float*)d_in[3];
  const float* bk = (const float*)d_in[4];
  const float* Wv = (const float*)d_in[5];
  const float* bv = (const float*)d_in[6];
  float* out = (float*)d_out;

  char* ws = (char*)d_ws;
  size_t off = 0;
  auto alloc = [&](size_t bytes) {
    char* p = ws + off;
    off += (bytes + 255) & ~255ull;
    return p;
  };
  _Float16* x16  = (_Float16*)alloc(8192ull * 1024 * 2);
  _Float16* W16  = (_Float16*)alloc(3072ull * 1024 * 2);
  _Float16* QKV  = (_Float16*)alloc(8192ull * 3072 * 2);
  _Float16* Vt   = (_Float16*)alloc(4096ull * 1024 * 4);
  _Float16* Sc   = (_Float16*)alloc(4ull * 2048 * 2048 * 2);
  float*    bcat = (float*)alloc(3072 * 4);
  if (off > ws_size) return;

  prep<<<3596, 256, 0, stream>>>(x, Wq, Wk, Wv, bq, bk, bv, x16, W16, bcat);

  gemmd<0><<<1536, 256, 0, stream>>>(x16, W16, QKV, bcat);
  transpose_v<<<dim3(32, 64, 4), 256, 0, stream>>>(QKV, Vt);

  gemm8x<<<256, 512, 0, stream>>>(QKV, Sc);
  softmax_rows_f16<<<8192, 256, 0, stream>>>(Sc);
  gemmd<2><<<512, 256, 0, stream>>>(Sc, Vt, out, nullptr);
}